// Round 6
// baseline (584.322 us; speedup 1.0000x reference)
//
#include <hip/hip_runtime.h>

#define T_ 64
#define B_ 1024
#define I_ 64
#define H_ 256

typedef short bf16x8 __attribute__((ext_vector_type(8)));
typedef float f32x4 __attribute__((ext_vector_type(4)));

#define MFMA16(a, b, c) __builtin_amdgcn_mfma_f32_16x16x32_bf16((a), (b), (c), 0, 0, 0)

__device__ __forceinline__ float bf2f(unsigned short u) {
    union { unsigned int i; float f; } x;
    x.i = ((unsigned int)u) << 16;
    return x.f;
}
__device__ __forceinline__ unsigned short f2bf(float f) {
    union { float f; unsigned int i; } x;
    x.f = f;
    unsigned int u = x.i;
    unsigned int r = u + 0x7FFFu + ((u >> 16) & 1u);
    return (unsigned short)(r >> 16);
}
__device__ __forceinline__ void split8(const float* p, bf16x8& hi, bf16x8& lo) {
#pragma unroll
    for (int q = 0; q < 8; ++q) {
        float f = p[q];
        unsigned short h1 = f2bf(f);
        hi[q] = (short)h1;
        lo[q] = (short)f2bf(f - bf2f(h1));
    }
}

// ---------------------------------------------------------------------------
// RNN: 64 blocks x 512 threads (8 waves). Unchanged (~263 us, CONTROL this
// round; counters still unseen — becomes top-5-visible when attn < 263).
// ---------------------------------------------------------------------------
__global__ __launch_bounds__(512) void rnn_kernel(
    const float* __restrict__ data,
    const float* __restrict__ h0,
    const float* __restrict__ Wih, const float* __restrict__ Whh,
    const float* __restrict__ bih, const float* __restrict__ bhh,
    unsigned short* __restrict__ hsHi, unsigned short* __restrict__ hsLo)
{
    __shared__ unsigned short hbuf[2][2][16 * 264];  // [buf][hi/lo][r*264+h]
    __shared__ float bsum[H_];

    const int tid  = threadIdx.x;
    const int lane = tid & 63;
    const int w    = tid >> 6;       // wave 0..7
    const int quad = lane >> 4;
    const int l15  = lane & 15;
    const int b0   = blockIdx.x * 16;

    // W in registers: wave w owns n-tiles 2w, 2w+1 (n = tile*16 + l15)
    bf16x8 whhH[2][8], whhL[2][8], wihH[2][2], wihL[2][2];
#pragma unroll
    for (int it = 0; it < 2; ++it) {
        int n = (w * 2 + it) * 16 + l15;
#pragma unroll
        for (int kc = 0; kc < 8; ++kc)
            split8(Whh + (size_t)n * H_ + kc * 32 + quad * 8, whhH[it][kc], whhL[it][kc]);
#pragma unroll
        for (int kx = 0; kx < 2; ++kx)
            split8(Wih + (size_t)n * I_ + kx * 32 + quad * 8, wihH[it][kx], wihL[it][kx]);
    }

    if (tid < H_) bsum[tid] = bih[tid] + bhh[tid];
    {   // stage h0 (fp32 -> hi/lo): 16 rows, 8 elems/thread
        int r  = tid >> 5;            // 0..15
        int hh = (tid & 31) * 8;      // 0..248
        const float* src = h0 + (size_t)(b0 + r) * H_ + hh;
#pragma unroll
        for (int q = 0; q < 8; ++q) {
            float f = src[q];
            unsigned short hi = f2bf(f);
            hbuf[0][0][r * 264 + hh + q] = hi;
            hbuf[0][1][r * 264 + hh + q] = f2bf(f - bf2f(hi));
        }
    }
    __syncthreads();

    // x prefetch registers (16 floats: 2 kx-chunks of 8)
    float xf[16];
    {
        const float* dp = data + ((size_t)(b0 + l15)) * I_ + quad * 8;
#pragma unroll
        for (int q = 0; q < 8; ++q) { xf[q] = dp[q]; xf[8 + q] = dp[32 + q]; }
    }

    int cur = 0;
    for (int t = 0; t < T_; ++t) {
        // convert prefetched x -> hi/lo
        bf16x8 xhi[2], xlo[2];
#pragma unroll
        for (int kx = 0; kx < 2; ++kx)
#pragma unroll
            for (int q = 0; q < 8; ++q) {
                float f = xf[kx * 8 + q];
                unsigned short h1 = f2bf(f);
                xhi[kx][q] = (short)h1;
                xlo[kx][q] = (short)f2bf(f - bf2f(h1));
            }
        // prefetch x for t+1 (overlaps the MFMA chain below)
        if (t + 1 < T_) {
            const float* dp = data + ((size_t)(t + 1) * B_ + b0 + l15) * I_ + quad * 8;
#pragma unroll
            for (int q = 0; q < 8; ++q) { xf[q] = dp[q]; xf[8 + q] = dp[32 + q]; }
        }

        f32x4 acc[2];
        acc[0] = (f32x4){0.f, 0.f, 0.f, 0.f};
        acc[1] = (f32x4){0.f, 0.f, 0.f, 0.f};

        // x @ Wih^T (3-term hi/lo)
#pragma unroll
        for (int kx = 0; kx < 2; ++kx) {
#pragma unroll
            for (int it = 0; it < 2; ++it) acc[it] = MFMA16(xhi[kx], wihH[it][kx], acc[it]);
#pragma unroll
            for (int it = 0; it < 2; ++it) acc[it] = MFMA16(xhi[kx], wihL[it][kx], acc[it]);
#pragma unroll
            for (int it = 0; it < 2; ++it) acc[it] = MFMA16(xlo[kx], wihH[it][kx], acc[it]);
        }
        // h @ Whh^T (3-term hi/lo), W from registers
#pragma unroll
        for (int kc = 0; kc < 8; ++kc) {
            bf16x8 ahi = *(const bf16x8*)&hbuf[cur][0][l15 * 264 + kc * 32 + quad * 8];
            bf16x8 alo = *(const bf16x8*)&hbuf[cur][1][l15 * 264 + kc * 32 + quad * 8];
#pragma unroll
            for (int it = 0; it < 2; ++it) acc[it] = MFMA16(ahi, whhH[it][kc], acc[it]);
#pragma unroll
            for (int it = 0; it < 2; ++it) acc[it] = MFMA16(ahi, whhL[it][kc], acc[it]);
#pragma unroll
            for (int it = 0; it < 2; ++it) acc[it] = MFMA16(alo, whhH[it][kc], acc[it]);
        }

        int nxt = cur ^ 1;
#pragma unroll
        for (int it = 0; it < 2; ++it) {
            int h = (w * 2 + it) * 16 + l15;
            float bs = bsum[h];
#pragma unroll
            for (int reg = 0; reg < 4; ++reg) {
                int r = quad * 4 + reg;                 // C/D: row = quad*4+reg, col = l15
                float v = acc[it][reg] + bs;
                v = fmaxf(v, 0.f);
                unsigned short hi = f2bf(v);
                unsigned short lo = f2bf(v - bf2f(hi));
                hbuf[nxt][0][r * 264 + h] = hi;
                hbuf[nxt][1][r * 264 + h] = lo;
            }
        }
        __syncthreads();
        // coalesced hs store from LDS: 512 thr x 16B per array
        {
            int r  = tid >> 5;
            int hc = (tid & 31) * 8;
            size_t g = ((size_t)t * B_ + b0 + r) * H_ + hc;
            *(bf16x8*)(hsHi + g) = *(const bf16x8*)&hbuf[nxt][0][r * 264 + hc];
            *(bf16x8*)(hsLo + g) = *(const bf16x8*)&hbuf[nxt][1][r * 264 + hc];
        }
        cur = nxt;
    }
}

// ---------------------------------------------------------------------------
// Attention + pred: 1024 blocks (one per b) x 256 threads (4 waves).
// R5: score accumulator split into 3 independent chains (HH / HL / LH),
// summed at the end. Was a 24-deep dependent MFMA chain (~380+ cy serial)
// per jslot; now 3x8-deep, 6 independent chains across both jslots ->
// SIMD can interleave. fp32 reassociation only (noise ~2^-24, << the
// bf16-quantization-driven 0.0625 absmax).
// Plain outAttn stores (R4 lesson: nt defeats L2 write-combining on this
// 4B scatter -> WRITE_SIZE 800 MB and store backpressure; plain = 264 MB).
// ---------------------------------------------------------------------------
__global__ __launch_bounds__(256) void attn_kernel(
    const unsigned short* __restrict__ hsHi,
    const unsigned short* __restrict__ hsLo,
    const int* __restrict__ nti,
    const float* __restrict__ Wlin,
    const float* __restrict__ blin,
    float* __restrict__ outPred,
    float* __restrict__ outAttn)
{
    __shared__ unsigned short GpH[18 * 264];   // rows jslot*9+n (0..17 valid)
    __shared__ unsigned short GpL[18 * 264];
    __shared__ unsigned short GpT[256 * 40];   // [h][k'=2n+jslot], cols 18..31 ZERO
    __shared__ float predc[64];
    __shared__ int   sidx[9];
    __shared__ float blin_s;

    const int tid  = threadIdx.x;
    const int lane = tid & 63;
    const int w    = tid >> 6;
    const int quad = lane >> 4;
    const int l15  = lane & 15;
    const int b    = blockIdx.x;

    if (tid == 0) blin_s = blin[0];
    if (tid < 9) sidx[tid] = nti[b * 9 + tid];
    for (int e = tid; e < 256 * 14; e += 256) {       // zero GpT cols k'=18..31 (once)
        int h = e / 14, c = 18 + e % 14;
        GpT[h * 40 + c] = 0;
    }

    // Hd hi/lo B-fragments (lane=col=i, regs=k=h) for this wave's 16 i-rows
    bf16x8 af[8], afl[8];
    {
        size_t base = ((size_t)(w * 16 + l15) * B_ + b) * H_;
#pragma unroll
        for (int kc = 0; kc < 8; ++kc) {
            af[kc]  = *(const bf16x8*)(hsHi + base + kc * 32 + quad * 8);
            afl[kc] = *(const bf16x8*)(hsLo + base + kc * 32 + quad * 8);
        }
    }
    f32x4 acc[16];
#pragma unroll
    for (int nt = 0; nt < 16; ++nt) acc[nt] = (f32x4){0.f, 0.f, 0.f, 0.f};
    __syncthreads();   // sidx/GpT zeros visible

    // gather prefetch registers: wave w handles n = w, w+4, w+8 (<9)
    ushort4 gh0[3], gl0[3], gh1[3], gl1[3];

#define ISSUE_GATHER(P)                                                        \
    {                                                                          \
        int j0g = 2 * (P);                                                     \
        _Pragma("unroll")                                                      \
        for (int c = 0; c < 3; ++c) {                                          \
            int n = w + 4 * c;                                                 \
            if (n < 9) {                                                       \
                int bi = sidx[n];                                              \
                if (bi < B_) {                                                 \
                    size_t base0 = ((size_t)j0g * B_ + bi) * H_;               \
                    size_t base1 = base0 + (size_t)B_ * H_;                    \
                    gh0[c] = ((const ushort4*)(hsHi + base0))[lane];           \
                    gl0[c] = ((const ushort4*)(hsLo + base0))[lane];           \
                    gh1[c] = ((const ushort4*)(hsHi + base1))[lane];           \
                    gl1[c] = ((const ushort4*)(hsLo + base1))[lane];           \
                } else {                                                       \
                    gh0[c].x=gh0[c].y=gh0[c].z=gh0[c].w=0;                     \
                    gl0[c].x=gl0[c].y=gl0[c].z=gl0[c].w=0;                     \
                    gh1[c].x=gh1[c].y=gh1[c].z=gh1[c].w=0;                     \
                    gl1[c].x=gl1[c].y=gl1[c].z=gl1[c].w=0;                     \
                }                                                              \
            }                                                                  \
        }                                                                      \
    }

    ISSUE_GATHER(0);

    for (int p = 0; p < 32; ++p) {
        int j0 = 2 * p;
        if (p) __syncthreads();          // prior compute done reading LDS
        // write prefetched gather to LDS
#pragma unroll
        for (int c = 0; c < 3; ++c) {
            int n = w + 4 * c;
            if (n < 9) {
                *(ushort4*)&GpH[n * 264 + lane * 4]       = gh0[c];
                *(ushort4*)&GpL[n * 264 + lane * 4]       = gl0[c];
                *(ushort4*)&GpH[(9 + n) * 264 + lane * 4] = gh1[c];
                *(ushort4*)&GpL[(9 + n) * 264 + lane * 4] = gl1[c];
                unsigned short h0v[4] = {gh0[c].x, gh0[c].y, gh0[c].z, gh0[c].w};
                unsigned short h1v[4] = {gh1[c].x, gh1[c].y, gh1[c].z, gh1[c].w};
#pragma unroll
                for (int q = 0; q < 4; ++q) {
                    ushort2 pr2; pr2.x = h0v[q]; pr2.y = h1v[q];
                    *(ushort2*)&GpT[(lane * 4 + q) * 40 + 2 * n] = pr2;
                }
            }
        }
        if (p < 31) ISSUE_GATHER(p + 1);     // loads in flight during compute
        __syncthreads();

        // --- scores S[n][i] (A = G rows from LDS, B = Hd regs), softmax, P ---
        unsigned short pmreg[2][4];          // masked P, this lane's (n,jslot) slots
#pragma unroll
        for (int jslot = 0; jslot < 2; ++jslot) {
            int j = j0 + jslot;
            int ar = jslot * 9 + l15;        // A row; rows >=18 would be overrun
            ar = (ar < 18) ? ar : 17;        // clamp: dup valid row, D row discarded
            // 3 independent accumulator chains (depth 8 each, was 24)
            f32x4 sA = (f32x4){0.f, 0.f, 0.f, 0.f};
            f32x4 sB = (f32x4){0.f, 0.f, 0.f, 0.f};
            f32x4 sC = (f32x4){0.f, 0.f, 0.f, 0.f};
#pragma unroll
            for (int kc = 0; kc < 8; ++kc) {
                bf16x8 aH = *(const bf16x8*)&GpH[ar * 264 + kc * 32 + quad * 8];
                bf16x8 aL = *(const bf16x8*)&GpL[ar * 264 + kc * 32 + quad * 8];
                sA = MFMA16(aH, af[kc],  sA);
                sB = MFMA16(aH, afl[kc], sB);
                sC = MFMA16(aL, af[kc],  sC);
            }
            f32x4 s = sA + sB + sC;
            // D[row=n=quad*4+reg][col=i=l15]; rows >=9 are garbage -> discarded
            int i = w * 16 + l15;
            int nvalid = (quad < 2) ? 4 : ((quad == 2) ? 1 : 0);
            float mp = -1e30f;
#pragma unroll
            for (int r = 0; r < 4; ++r) if (r < nvalid) mp = fmaxf(mp, s[r]);
            mp = fmaxf(mp, __shfl_xor(mp, 16, 64));
            mp = fmaxf(mp, __shfl_xor(mp, 32, 64));
            float e[4], sp = 0.f;
#pragma unroll
            for (int r = 0; r < 4; ++r) {
                e[r] = (r < nvalid) ? __expf(s[r] - mp) : 0.f;
                sp += e[r];
            }
            sp += __shfl_xor(sp, 16, 64);
            sp += __shfl_xor(sp, 32, 64);
            float inv = 1.f / sp;
#pragma unroll
            for (int r = 0; r < 4; ++r) {
                pmreg[jslot][r] = 0;
                if (r < nvalid) {
                    int n = quad * 4 + r;
                    float pr = e[r] * inv;
                    outAttn[(((size_t)i * T_ + j) * B_ + b) * 9 + n] = pr;
                    pmreg[jslot][r] = (j < i) ? f2bf(pr) : (unsigned short)0;
                }
            }
        }

        // --- c += P @ G (K=32, k'-interleaved); A-frag packed in-register ---
        {
            bf16x8 afp;
#pragma unroll
            for (int q = 0; q < 8; ++q) afp[q] = (short)pmreg[q & 1][q >> 1];
#pragma unroll
            for (int nt = 0; nt < 16; ++nt) {
                bf16x8 bfg = *(const bf16x8*)&GpT[(nt * 16 + l15) * 40 + quad * 8];
                acc[nt] = MFMA16(afp, bfg, acc[nt]);
            }
        }
    }

    // --- fused pred epilogue (Wlin from L2) ---
    float hw1 = 0.f, hw2 = 0.f;    // hs[i].W1, hs[i].W2 (i = w*16 + l15)
#pragma unroll
    for (int kc = 0; kc < 8; ++kc) {
#pragma unroll
        for (int jj = 0; jj < 8; ++jj) {
            float hv = bf2f((unsigned short)af[kc][jj]) + bf2f((unsigned short)afl[kc][jj]);
            int h = kc * 32 + quad * 8 + jj;
            hw1 += hv * Wlin[h];
            hw2 += hv * Wlin[H_ + h];
        }
    }
    hw1 += __shfl_xor(hw1, 16, 64); hw1 += __shfl_xor(hw1, 32, 64);
    hw2 += __shfl_xor(hw2, 16, 64); hw2 += __shfl_xor(hw2, 32, 64);

#pragma unroll
    for (int reg = 0; reg < 4; ++reg) {            // c[i].W1 from accumulators
        float cp = 0.f;
#pragma unroll
        for (int nt = 0; nt < 16; ++nt)
            cp += acc[nt][reg] * Wlin[nt * 16 + l15];
        for (int m = 8; m >= 1; m >>= 1) cp += __shfl_xor(cp, m, 16);
        if (l15 == 0) predc[w * 16 + quad * 4 + reg] = cp;
    }
    __syncthreads();
    if (lane < 16) {
        int i = w * 16 + lane;
        float v = predc[i] + hw2 + ((i == 0) ? hw1 : 0.f) + blin_s;
        v = fmaxf(v, 0.f);
        outPred[(size_t)i * B_ + b] = v;
    }
}

extern "C" void kernel_launch(void* const* d_in, const int* in_sizes, int n_in,
                              void* d_out, int out_size, void* d_ws, size_t ws_size,
                              hipStream_t stream) {
    (void)in_sizes; (void)n_in; (void)out_size; (void)ws_size;
    const float* data = (const float*)d_in[0];
    const int*   nti  = (const int*)d_in[1];
    // d_in[2] haven_flag == 0 always
    const float* h0   = (const float*)d_in[3];
    const float* Wih  = (const float*)d_in[4];
    const float* Whh  = (const float*)d_in[5];
    const float* bih  = (const float*)d_in[6];
    const float* bhh  = (const float*)d_in[7];
    const float* Wlin = (const float*)d_in[8];
    const float* blin = (const float*)d_in[9];

    unsigned short* ws = (unsigned short*)d_ws;
    unsigned short* hsHi = ws;                                    // T*B*H
    unsigned short* hsLo = ws + (size_t)T_ * B_ * H_;             // T*B*H

    float* outPred = (float*)d_out;                               // (T,B,1)
    float* outAttn = (float*)d_out + (size_t)T_ * B_;             // (T,T,B,9)

    rnn_kernel<<<dim3(64), dim3(512), 0, stream>>>(data, h0, Wih, Whh, bih, bhh, hsHi, hsLo);
    attn_kernel<<<dim3(1024), dim3(256), 0, stream>>>(hsHi, hsLo, nti, Wlin, blin,
                                                      outPred, outAttn);
}

// Round 10
// 555.415 us; speedup vs baseline: 1.0520x; 1.0520x over previous
//
#include <hip/hip_runtime.h>

#define T_ 64
#define B_ 1024
#define I_ 64
#define H_ 256

typedef short bf16x8 __attribute__((ext_vector_type(8)));
typedef float f32x4 __attribute__((ext_vector_type(4)));

#define MFMA16(a, b, c) __builtin_amdgcn_mfma_f32_16x16x32_bf16((a), (b), (c), 0, 0, 0)

__device__ __forceinline__ float bf2f(unsigned short u) {
    union { unsigned int i; float f; } x;
    x.i = ((unsigned int)u) << 16;
    return x.f;
}
__device__ __forceinline__ unsigned short f2bf(float f) {
    union { float f; unsigned int i; } x;
    x.f = f;
    unsigned int u = x.i;
    unsigned int r = u + 0x7FFFu + ((u >> 16) & 1u);
    return (unsigned short)(r >> 16);
}
__device__ __forceinline__ void split8(const float* p, bf16x8& hi, bf16x8& lo) {
#pragma unroll
    for (int q = 0; q < 8; ++q) {
        float f = p[q];
        unsigned short h1 = f2bf(f);
        hi[q] = (short)h1;
        lo[q] = (short)f2bf(f - bf2f(h1));
    }
}

// ---------------------------------------------------------------------------
// RNN: 64 blocks x 512 threads (8 waves, 1 block/CU -> only 2 waves/SIMD).
// R9: accumulator chains split 2 -> 6 (by hi/lo term type, like R5 in attn).
// At 2 waves/SIMD the 30-deep dependent MFMA chains (~16cy dep latency vs
// ~5cy issue) can't be hidden by TLP; 6 independent depth-10 chains/wave
// give the SIMD enough ILP. fp32 reassociation only (R5 precedent: absmax
// unchanged). +16 VGPR, under the 256 cap at 2 waves/SIMD.
// ---------------------------------------------------------------------------
__global__ __launch_bounds__(512) void rnn_kernel(
    const float* __restrict__ data,
    const float* __restrict__ h0,
    const float* __restrict__ Wih, const float* __restrict__ Whh,
    const float* __restrict__ bih, const float* __restrict__ bhh,
    unsigned short* __restrict__ hsHi, unsigned short* __restrict__ hsLo)
{
    __shared__ unsigned short hbuf[2][2][16 * 264];  // [buf][hi/lo][r*264+h]
    __shared__ float bsum[H_];

    const int tid  = threadIdx.x;
    const int lane = tid & 63;
    const int w    = tid >> 6;       // wave 0..7
    const int quad = lane >> 4;
    const int l15  = lane & 15;
    const int b0   = blockIdx.x * 16;

    // W in registers: wave w owns n-tiles 2w, 2w+1 (n = tile*16 + l15)
    bf16x8 whhH[2][8], whhL[2][8], wihH[2][2], wihL[2][2];
#pragma unroll
    for (int it = 0; it < 2; ++it) {
        int n = (w * 2 + it) * 16 + l15;
#pragma unroll
        for (int kc = 0; kc < 8; ++kc)
            split8(Whh + (size_t)n * H_ + kc * 32 + quad * 8, whhH[it][kc], whhL[it][kc]);
#pragma unroll
        for (int kx = 0; kx < 2; ++kx)
            split8(Wih + (size_t)n * I_ + kx * 32 + quad * 8, wihH[it][kx], wihL[it][kx]);
    }

    if (tid < H_) bsum[tid] = bih[tid] + bhh[tid];
    {   // stage h0 (fp32 -> hi/lo): 16 rows, 8 elems/thread
        int r  = tid >> 5;            // 0..15
        int hh = (tid & 31) * 8;      // 0..248
        const float* src = h0 + (size_t)(b0 + r) * H_ + hh;
#pragma unroll
        for (int q = 0; q < 8; ++q) {
            float f = src[q];
            unsigned short hi = f2bf(f);
            hbuf[0][0][r * 264 + hh + q] = hi;
            hbuf[0][1][r * 264 + hh + q] = f2bf(f - bf2f(hi));
        }
    }
    __syncthreads();

    // x prefetch registers (16 floats: 2 kx-chunks of 8)
    float xf[16];
    {
        const float* dp = data + ((size_t)(b0 + l15)) * I_ + quad * 8;
#pragma unroll
        for (int q = 0; q < 8; ++q) { xf[q] = dp[q]; xf[8 + q] = dp[32 + q]; }
    }

    int cur = 0;
    for (int t = 0; t < T_; ++t) {
        // convert prefetched x -> hi/lo
        bf16x8 xhi[2], xlo[2];
#pragma unroll
        for (int kx = 0; kx < 2; ++kx)
#pragma unroll
            for (int q = 0; q < 8; ++q) {
                float f = xf[kx * 8 + q];
                unsigned short h1 = f2bf(f);
                xhi[kx][q] = (short)h1;
                xlo[kx][q] = (short)f2bf(f - bf2f(h1));
            }
        // prefetch x for t+1 (overlaps the MFMA chain below)
        if (t + 1 < T_) {
            const float* dp = data + ((size_t)(t + 1) * B_ + b0 + l15) * I_ + quad * 8;
#pragma unroll
            for (int q = 0; q < 8; ++q) { xf[q] = dp[q]; xf[8 + q] = dp[32 + q]; }
        }

        // 6 independent chains: cA=hi*WH, cB=hi*WL, cC=lo*WH, for it=0,1
        f32x4 cA[2], cB[2], cC[2];
#pragma unroll
        for (int it = 0; it < 2; ++it) {
            cA[it] = (f32x4){0.f, 0.f, 0.f, 0.f};
            cB[it] = (f32x4){0.f, 0.f, 0.f, 0.f};
            cC[it] = (f32x4){0.f, 0.f, 0.f, 0.f};
        }

        // x @ Wih^T (3-term hi/lo, split chains)
#pragma unroll
        for (int kx = 0; kx < 2; ++kx) {
#pragma unroll
            for (int it = 0; it < 2; ++it) cA[it] = MFMA16(xhi[kx], wihH[it][kx], cA[it]);
#pragma unroll
            for (int it = 0; it < 2; ++it) cB[it] = MFMA16(xhi[kx], wihL[it][kx], cB[it]);
#pragma unroll
            for (int it = 0; it < 2; ++it) cC[it] = MFMA16(xlo[kx], wihH[it][kx], cC[it]);
        }
        // h @ Whh^T (3-term hi/lo, split chains), W from registers
#pragma unroll
        for (int kc = 0; kc < 8; ++kc) {
            bf16x8 ahi = *(const bf16x8*)&hbuf[cur][0][l15 * 264 + kc * 32 + quad * 8];
            bf16x8 alo = *(const bf16x8*)&hbuf[cur][1][l15 * 264 + kc * 32 + quad * 8];
#pragma unroll
            for (int it = 0; it < 2; ++it) cA[it] = MFMA16(ahi, whhH[it][kc], cA[it]);
#pragma unroll
            for (int it = 0; it < 2; ++it) cB[it] = MFMA16(ahi, whhL[it][kc], cB[it]);
#pragma unroll
            for (int it = 0; it < 2; ++it) cC[it] = MFMA16(alo, whhH[it][kc], cC[it]);
        }

        int nxt = cur ^ 1;
#pragma unroll
        for (int it = 0; it < 2; ++it) {
            int h = (w * 2 + it) * 16 + l15;
            float bs = bsum[h];
#pragma unroll
            for (int reg = 0; reg < 4; ++reg) {
                int r = quad * 4 + reg;                 // C/D: row = quad*4+reg, col = l15
                float v = (cA[it][reg] + cB[it][reg] + cC[it][reg]) + bs;
                v = fmaxf(v, 0.f);
                unsigned short hi = f2bf(v);
                unsigned short lo = f2bf(v - bf2f(hi));
                hbuf[nxt][0][r * 264 + h] = hi;
                hbuf[nxt][1][r * 264 + h] = lo;
            }
        }
        __syncthreads();
        // coalesced hs store from LDS: 512 thr x 16B per array
        {
            int r  = tid >> 5;
            int hc = (tid & 31) * 8;
            size_t g = ((size_t)t * B_ + b0 + r) * H_ + hc;
            *(bf16x8*)(hsHi + g) = *(const bf16x8*)&hbuf[nxt][0][r * 264 + hc];
            *(bf16x8*)(hsLo + g) = *(const bf16x8*)&hbuf[nxt][1][r * 264 + hc];
        }
        cur = nxt;
    }
}

// ---------------------------------------------------------------------------
// Attention + pred: 1024 blocks (one per b) x 256 threads (4 waves).
// R6 (UNMEASURED, 3 infra failures): GpT physical-row permutation
// h' = (h>>2) + (h&3)*64 (bijective). The old write `GpT[(lane*4+q)*40+2n]`
// had lane-stride 80 dwords == 16 mod 32 -> 64 lanes on 2 banks = 32-way
// conflict = 62% of the 6.06e7 SQ_LDS_BANK_CONFLICT. Permuted write row
// lane+64q -> bank (20*lane+n)%32 -> 8-way; PV read -> conflict-free.
// Pure layout change, bit-identical values.
// Plain outAttn stores (R4 lesson: nt defeats L2 write-combining -> 800 MB).
// R5's 3-chain score split kept.
// ---------------------------------------------------------------------------
__global__ __launch_bounds__(256) void attn_kernel(
    const unsigned short* __restrict__ hsHi,
    const unsigned short* __restrict__ hsLo,
    const int* __restrict__ nti,
    const float* __restrict__ Wlin,
    const float* __restrict__ blin,
    float* __restrict__ outPred,
    float* __restrict__ outAttn)
{
    __shared__ unsigned short GpH[18 * 264];   // rows jslot*9+n (0..17 valid)
    __shared__ unsigned short GpL[18 * 264];
    __shared__ unsigned short GpT[256 * 40];   // PHYS rows h'=(h>>2)+(h&3)*64; [h'][k'], cols 18..31 ZERO
    __shared__ float predc[64];
    __shared__ int   sidx[9];
    __shared__ float blin_s;

    const int tid  = threadIdx.x;
    const int lane = tid & 63;
    const int w    = tid >> 6;
    const int quad = lane >> 4;
    const int l15  = lane & 15;
    const int b    = blockIdx.x;

    if (tid == 0) blin_s = blin[0];
    if (tid < 9) sidx[tid] = nti[b * 9 + tid];
    for (int e = tid; e < 256 * 14; e += 256) {       // zero GpT cols k'=18..31 (all phys rows)
        int h = e / 14, c = 18 + e % 14;
        GpT[h * 40 + c] = 0;
    }

    // Hd hi/lo B-fragments (lane=col=i, regs=k=h) for this wave's 16 i-rows
    bf16x8 af[8], afl[8];
    {
        size_t base = ((size_t)(w * 16 + l15) * B_ + b) * H_;
#pragma unroll
        for (int kc = 0; kc < 8; ++kc) {
            af[kc]  = *(const bf16x8*)(hsHi + base + kc * 32 + quad * 8);
            afl[kc] = *(const bf16x8*)(hsLo + base + kc * 32 + quad * 8);
        }
    }
    f32x4 acc[16];
#pragma unroll
    for (int nt = 0; nt < 16; ++nt) acc[nt] = (f32x4){0.f, 0.f, 0.f, 0.f};
    __syncthreads();   // sidx/GpT zeros visible

    // gather prefetch registers: wave w handles n = w, w+4, w+8 (<9)
    ushort4 gh0[3], gl0[3], gh1[3], gl1[3];

#define ISSUE_GATHER(P)                                                        \
    {                                                                          \
        int j0g = 2 * (P);                                                     \
        _Pragma("unroll")                                                      \
        for (int c = 0; c < 3; ++c) {                                          \
            int n = w + 4 * c;                                                 \
            if (n < 9) {                                                       \
                int bi = sidx[n];                                              \
                if (bi < B_) {                                                 \
                    size_t base0 = ((size_t)j0g * B_ + bi) * H_;               \
                    size_t base1 = base0 + (size_t)B_ * H_;                    \
                    gh0[c] = ((const ushort4*)(hsHi + base0))[lane];           \
                    gl0[c] = ((const ushort4*)(hsLo + base0))[lane];           \
                    gh1[c] = ((const ushort4*)(hsHi + base1))[lane];           \
                    gl1[c] = ((const ushort4*)(hsLo + base1))[lane];           \
                } else {                                                       \
                    gh0[c].x=gh0[c].y=gh0[c].z=gh0[c].w=0;                     \
                    gl0[c].x=gl0[c].y=gl0[c].z=gl0[c].w=0;                     \
                    gh1[c].x=gh1[c].y=gh1[c].z=gh1[c].w=0;                     \
                    gl1[c].x=gl1[c].y=gl1[c].z=gl1[c].w=0;                     \
                }                                                              \
            }                                                                  \
        }                                                                      \
    }

    ISSUE_GATHER(0);

    for (int p = 0; p < 32; ++p) {
        int j0 = 2 * p;
        if (p) __syncthreads();          // prior compute done reading LDS
        // write prefetched gather to LDS
#pragma unroll
        for (int c = 0; c < 3; ++c) {
            int n = w + 4 * c;
            if (n < 9) {
                *(ushort4*)&GpH[n * 264 + lane * 4]       = gh0[c];
                *(ushort4*)&GpL[n * 264 + lane * 4]       = gl0[c];
                *(ushort4*)&GpH[(9 + n) * 264 + lane * 4] = gh1[c];
                *(ushort4*)&GpL[(9 + n) * 264 + lane * 4] = gl1[c];
                unsigned short h0v[4] = {gh0[c].x, gh0[c].y, gh0[c].z, gh0[c].w};
                unsigned short h1v[4] = {gh1[c].x, gh1[c].y, gh1[c].z, gh1[c].w};
#pragma unroll
                for (int q = 0; q < 4; ++q) {
                    // logical row h = lane*4+q  ->  phys row = lane + 64q
                    ushort2 pr2; pr2.x = h0v[q]; pr2.y = h1v[q];
                    *(ushort2*)&GpT[(lane + q * 64) * 40 + 2 * n] = pr2;
                }
            }
        }
        if (p < 31) ISSUE_GATHER(p + 1);     // loads in flight during compute
        __syncthreads();

        // --- scores S[n][i] (A = G rows from LDS, B = Hd regs), softmax, P ---
        unsigned short pmreg[2][4];          // masked P, this lane's (n,jslot) slots
#pragma unroll
        for (int jslot = 0; jslot < 2; ++jslot) {
            int j = j0 + jslot;
            int ar = jslot * 9 + l15;        // A row; rows >=18 would be overrun
            ar = (ar < 18) ? ar : 17;        // clamp: dup valid row, D row discarded
            // 3 independent accumulator chains (depth 8 each)
            f32x4 sA = (f32x4){0.f, 0.f, 0.f, 0.f};
            f32x4 sB = (f32x4){0.f, 0.f, 0.f, 0.f};
            f32x4 sC = (f32x4){0.f, 0.f, 0.f, 0.f};
#pragma unroll
            for (int kc = 0; kc < 8; ++kc) {
                bf16x8 aH = *(const bf16x8*)&GpH[ar * 264 + kc * 32 + quad * 8];
                bf16x8 aL = *(const bf16x8*)&GpL[ar * 264 + kc * 32 + quad * 8];
                sA = MFMA16(aH, af[kc],  sA);
                sB = MFMA16(aH, afl[kc], sB);
                sC = MFMA16(aL, af[kc],  sC);
            }
            f32x4 s = sA + sB + sC;
            // D[row=n=quad*4+reg][col=i=l15]; rows >=9 are garbage -> discarded
            int i = w * 16 + l15;
            int nvalid = (quad < 2) ? 4 : ((quad == 2) ? 1 : 0);
            float mp = -1e30f;
#pragma unroll
            for (int r = 0; r < 4; ++r) if (r < nvalid) mp = fmaxf(mp, s[r]);
            mp = fmaxf(mp, __shfl_xor(mp, 16, 64));
            mp = fmaxf(mp, __shfl_xor(mp, 32, 64));
            float e[4], sp = 0.f;
#pragma unroll
            for (int r = 0; r < 4; ++r) {
                e[r] = (r < nvalid) ? __expf(s[r] - mp) : 0.f;
                sp += e[r];
            }
            sp += __shfl_xor(sp, 16, 64);
            sp += __shfl_xor(sp, 32, 64);
            float inv = 1.f / sp;
#pragma unroll
            for (int r = 0; r < 4; ++r) {
                pmreg[jslot][r] = 0;
                if (r < nvalid) {
                    int n = quad * 4 + r;
                    float pr = e[r] * inv;
                    outAttn[(((size_t)i * T_ + j) * B_ + b) * 9 + n] = pr;
                    pmreg[jslot][r] = (j < i) ? f2bf(pr) : (unsigned short)0;
                }
            }
        }

        // --- c += P @ G (K=32, k'-interleaved); A-frag packed in-register ---
        {
            bf16x8 afp;
#pragma unroll
            for (int q = 0; q < 8; ++q) afp[q] = (short)pmreg[q & 1][q >> 1];
            // logical row h = nt*16+l15 -> phys = nt*4 + (l15>>2) + (l15&3)*64
            const int prow_base = (l15 >> 2) + (l15 & 3) * 64;
#pragma unroll
            for (int nt = 0; nt < 16; ++nt) {
                bf16x8 bfg = *(const bf16x8*)&GpT[(prow_base + nt * 4) * 40 + quad * 8];
                acc[nt] = MFMA16(afp, bfg, acc[nt]);
            }
        }
    }

    // --- fused pred epilogue (Wlin from L2) ---
    float hw1 = 0.f, hw2 = 0.f;    // hs[i].W1, hs[i].W2 (i = w*16 + l15)
#pragma unroll
    for (int kc = 0; kc < 8; ++kc) {
#pragma unroll
        for (int jj = 0; jj < 8; ++jj) {
            float hv = bf2f((unsigned short)af[kc][jj]) + bf2f((unsigned short)afl[kc][jj]);
            int h = kc * 32 + quad * 8 + jj;
            hw1 += hv * Wlin[h];
            hw2 += hv * Wlin[H_ + h];
        }
    }
    hw1 += __shfl_xor(hw1, 16, 64); hw1 += __shfl_xor(hw1, 32, 64);
    hw2 += __shfl_xor(hw2, 16, 64); hw2 += __shfl_xor(hw2, 32, 64);

#pragma unroll
    for (int reg = 0; reg < 4; ++reg) {            // c[i].W1 from accumulators
        float cp = 0.f;
#pragma unroll
        for (int nt = 0; nt < 16; ++nt)
            cp += acc[nt][reg] * Wlin[nt * 16 + l15];
        for (int m = 8; m >= 1; m >>= 1) cp += __shfl_xor(cp, m, 16);
        if (l15 == 0) predc[w * 16 + quad * 4 + reg] = cp;
    }
    __syncthreads();
    if (lane < 16) {
        int i = w * 16 + lane;
        float v = predc[i] + hw2 + ((i == 0) ? hw1 : 0.f) + blin_s;
        v = fmaxf(v, 0.f);
        outPred[(size_t)i * B_ + b] = v;
    }
}

extern "C" void kernel_launch(void* const* d_in, const int* in_sizes, int n_in,
                              void* d_out, int out_size, void* d_ws, size_t ws_size,
                              hipStream_t stream) {
    (void)in_sizes; (void)n_in; (void)out_size; (void)ws_size;
    const float* data = (const float*)d_in[0];
    const int*   nti  = (const int*)d_in[1];
    // d_in[2] haven_flag == 0 always
    const float* h0   = (const float*)d_in[3];
    const float* Wih  = (const float*)d_in[4];
    const float* Whh  = (const float*)d_in[5];
    const float* bih  = (const float*)d_in[6];
    const float* bhh  = (const float*)d_in[7];
    const float* Wlin = (const float*)d_in[8];
    const float* blin = (const float*)d_in[9];

    unsigned short* ws = (unsigned short*)d_ws;
    unsigned short* hsHi = ws;                                    // T*B*H
    unsigned short* hsLo = ws + (size_t)T_ * B_ * H_;             // T*B*H

    float* outPred = (float*)d_out;                               // (T,B,1)
    float* outAttn = (float*)d_out + (size_t)T_ * B_;             // (T,T,B,9)

    rnn_kernel<<<dim3(64), dim3(512), 0, stream>>>(data, h0, Wih, Whh, bih, bhh, hsHi, hsLo);
    attn_kernel<<<dim3(1024), dim3(256), 0, stream>>>(hsHi, hsLo, nti, Wlin, blin,
                                                      outPred, outAttn);
}